// Round 1
// baseline (187.331 us; speedup 1.0000x reference)
//
#include <hip/hip_runtime.h>
#include <math.h>

// Problem constants (B=2, S=2048, D=1024, H=16, dh=64)
#define S_LEN 2048

using bf16x8  = __attribute__((ext_vector_type(8))) short;  // 8 bf16 (4 VGPRs)
using shortx4 = __attribute__((ext_vector_type(4))) short;  // ds_write_b64
using f32x4   = __attribute__((ext_vector_type(4))) float;  // MFMA accumulator
using uintx4  = __attribute__((ext_vector_type(4))) unsigned;
using uintx2  = __attribute__((ext_vector_type(2))) unsigned;

static __device__ __forceinline__ short f2bf(float f) {
  unsigned u = __float_as_uint(f);
  u += 0x7fffu + ((u >> 16) & 1u);
  return (short)(u >> 16);
}

#if __has_builtin(__builtin_amdgcn_cvt_pk_bf16_f32)
using bf16x2_t = __attribute__((ext_vector_type(2))) __bf16;
static __device__ __forceinline__ unsigned pkbf(float a, float b) {
  bf16x2_t v = __builtin_amdgcn_cvt_pk_bf16_f32(a, b);
  return __builtin_bit_cast(unsigned, v);
}
#else
static __device__ __forceinline__ unsigned pkbf(float a, float b) {
  return (unsigned)(unsigned short)f2bf(a) | ((unsigned)(unsigned short)f2bf(b) << 16);
}
#endif

// Direct global->LDS DMA, 16B per lane. LDS dest = wave-uniform base + lane*16.
#define GLD_LDS16(gptr, lptr)                                                  \
  __builtin_amdgcn_global_load_lds(                                            \
      (__attribute__((address_space(1))) void*)(gptr),                         \
      (__attribute__((address_space(3))) void*)(lptr), 16, 0, 0)

// exp2 shift: softmax is shift-invariant; scores ~N(0,1) so 2^(s*log2e-20)
// never overflows and l ~ 2e-3 stays comfortably normal in fp32.
#define EXP2_SHIFT 20.0f

static __device__ __forceinline__ f32x4 exp2s4(f32x4 a) {
  return (f32x4){__builtin_amdgcn_exp2f(a[0] - EXP2_SHIFT),
                 __builtin_amdgcn_exp2f(a[1] - EXP2_SHIFT),
                 __builtin_amdgcn_exp2f(a[2] - EXP2_SHIFT),
                 __builtin_amdgcn_exp2f(a[3] - EXP2_SHIFT)};
}

// Key permutation for VT (see prep_v / attn_mfma).
static __device__ __forceinline__ int sigma64(int k) {
  return (k & 0x20) | ((k & 0x0C) << 1) | ((k & 0x10) >> 2) | (k & 3);
}

// ---------------------------------------------------------------------------
// Fused init: fp32->bf16 casts + RoPE cos/sin table (fp64 trig for range red).
// ---------------------------------------------------------------------------
__global__ __launch_bounds__(256) void init_kernel(const float* __restrict__ X,
                                                   const float* __restrict__ W1,
                                                   const float* __restrict__ W2,
                                                   const int* __restrict__ tok,
                                                   short* __restrict__ Xb,
                                                   short* __restrict__ W1b,
                                                   short* __restrict__ W2b,
                                                   float2* __restrict__ table) {
  if (blockIdx.x < 4096) {
    size_t idx = (size_t)(blockIdx.x * 256 + threadIdx.x) * 8;
    const float* src;
    short* dst;
    size_t off;
    if (idx < 4194304) { src = X; dst = Xb; off = idx; }
    else if (idx < 4194304 + 3145728) { src = W1; dst = W1b; off = idx - 4194304; }
    else { src = W2; dst = W2b; off = idx - (4194304 + 3145728); }
    float4 a = *(const float4*)(src + off);
    float4 b = *(const float4*)(src + off + 4);
    bf16x8 o = {f2bf(a.x), f2bf(a.y), f2bf(a.z), f2bf(a.w),
                f2bf(b.x), f2bf(b.y), f2bf(b.z), f2bf(b.w)};
    *(bf16x8*)(dst + off) = o;
  } else {
    int i = (blockIdx.x - 4096) * 256 + threadIdx.x;  // [0, 65536)
    int s = i >> 5, j = i & 31;
    double pos = (double)tok[s];
    double ang = pos * pow(10000.0, -(double)j / 32.0);
    table[i] = make_float2((float)cos(ang), (float)sin(ang));
  }
}

// ---------------------------------------------------------------------------
// QKV GEMM, deep-pipelined 256x256 tile (T3+T4+T5 schedule):
//   C[4096,3072] = Xb[4096,1024] . Wqkv[3072,1024]^T, fused RoPE epilogue.
// 512 thr = 8 waves (2M x 4N); per-wave C = 128x64 (acc[8][4] f32x4).
// BK=32; LDS = ring of 4 K-step slots x (A 16KB + B 16KB) = 128 KiB
// (1 block/CU).  Staging runs 3 K-steps ahead via global_load_lds; raw
// s_barrier (NO implicit vmcnt drain) + counted s_waitcnt vmcnt(8) once per
// K-step keep 8 loads/thread in flight across barriers.  Two phases per
// K-step, each: {ds_read frags | stage 2xGLD | barrier | setprio(1) 16 MFMA
// setprio(0) | barrier}.  XOR-swizzled LDS chunks (proven 0 conflicts).
// Grid: 192 blocks, bijective XCD swizzle, row-chunked (24 blocks/XCD share
// 2 A-panels -> L2-resident; B panels stream from L3).
// ---------------------------------------------------------------------------
__global__ __launch_bounds__(512, 2) void gemm256_qkv(const short* __restrict__ A,
                                                      const short* __restrict__ B,
                                                      const float2* __restrict__ tab,
                                                      short* __restrict__ Qb,
                                                      short* __restrict__ Kb,
                                                      short* __restrict__ Vb) {
  constexpr int K = 1024;
  constexpr int NT = K / 32;               // 32 K-steps
  __shared__ short smem[65536];            // [A: 4 x 8192 | B: 4 x 8192] shorts

  const int tid  = threadIdx.x;
  const int lane = tid & 63;
  const int wv   = tid >> 6;               // wave 0..7
  const int m16  = lane & 15;
  const int q4   = lane >> 4;

  // bijective XCD swizzle (nwg=192, 192%8==0): xcd gets 24 consecutive ids,
  // row-major chunking -> each XCD's resident blocks share 2 A-panels.
  const int wg  = blockIdx.x;
  const int wgs = (wg & 7) * 24 + (wg >> 3);
  const int cx  = wgs % 12, cy = wgs / 12;
  const int rowBase = cy * 256;
  const int colBase = cx * 256;

  const int wmr = (wv >> 2) * 128;         // wave M offset within tile
  const int wnr = (wv & 3) * 64;           // wave N offset within tile

  const int lrow = lane >> 2;                      // staging row in 16-row group
  const int lchk = (lane & 3) ^ ((lane >> 3) & 3); // swizzled k-chunk to fetch
  const int fsw  = (q4 ^ ((m16 >> 1) & 3)) * 8;    // swizzled frag k-offset

  const short* Agl = A + (size_t)rowBase * K;
  const short* Bgl = B + (size_t)colBase * K;

  // per-thread staging base addresses (2 GLD calls each for A and B per step)
  const short* Ath0 = Agl + (size_t)((wv * 2 + 0) * 16 + lrow) * K + lchk * 8;
  const short* Ath1 = Agl + (size_t)((wv * 2 + 1) * 16 + lrow) * K + lchk * 8;
  const short* Bth0 = Bgl + (size_t)((wv * 2 + 0) * 16 + lrow) * K + lchk * 8;
  const short* Bth1 = Bgl + (size_t)((wv * 2 + 1) * 16 + lrow) * K + lchk * 8;
  const int lA0 = wv * 1024;               // (wv*2+0)*16 rows * 32 shorts
  const int lA1 = wv * 1024 + 512;

#define STAGE_A(s)                                                             \
  do {                                                                         \
    const int _sl = ((s) & 3) * 8192;                                          \
    GLD_LDS16(Ath0 + (size_t)(s) * 32, &smem[_sl + lA0]);                      \
    GLD_LDS16(Ath1 + (size_t)(s) * 32, &smem[_sl + lA1]);                      \
  } while (0)
#define STAGE_B(s)                                                             \
  do {                                                                         \
    const int _sl = 32768 + ((s) & 3) * 8192;                                  \
    GLD_LDS16(Bth0 + (size_t)(s) * 32, &smem[_sl + lA0]);                      \
    GLD_LDS16(Bth1 + (size_t)(s) * 32, &smem[_sl + lA1]);                      \
  } while (0)

  f32x4 acc[8][4];
#pragma unroll
  for (int i = 0; i < 8; ++i)
#pragma unroll
    for (int j = 0; j < 4; ++j) acc[i][j] = (f32x4){0.f, 0.f, 0.f, 0.f};

  // prologue: stage steps 0,1,2 (12 loads/thread); wait step 0 (8 remain)
  STAGE_A(0); STAGE_B(0);
  STAGE_A(1); STAGE_B(1);
  STAGE_A(2); STAGE_B(2);
  asm volatile("s_waitcnt vmcnt(8)" ::: "memory");
  __builtin_amdgcn_s_barrier();
  __builtin_amdgcn_sched_barrier(0);

  for (int t = 0; t < NT; ++t) {
    const short* As = &smem[(t & 3) * 8192];
    const short* Bs = &smem[32768 + (t & 3) * 8192];

    // ---- phase 0: B frags + A frags mi0-3; stage A(t+3); 16 MFMA ----
    bf16x8 bF[4], aF0[4], aF1[4];
#pragma unroll
    for (int ni = 0; ni < 4; ++ni)
      bF[ni] = *(const bf16x8*)&Bs[(wnr + ni * 16 + m16) * 32 + fsw];
#pragma unroll
    for (int mi = 0; mi < 4; ++mi)
      aF0[mi] = *(const bf16x8*)&As[(wmr + mi * 16 + m16) * 32 + fsw];
    if (t + 3 < NT) STAGE_A(t + 3);
    __builtin_amdgcn_s_barrier();
    __builtin_amdgcn_s_setprio(1);
#pragma unroll
    for (int mi = 0; mi < 4; ++mi)
#pragma unroll
      for (int ni = 0; ni < 4; ++ni)
        acc[mi][ni] = __builtin_amdgcn_mfma_f32_16x16x32_bf16(aF0[mi], bF[ni], acc[mi][ni], 0, 0, 0);
    __builtin_amdgcn_s_setprio(0);
    __builtin_amdgcn_s_barrier();

    // ---- phase 1: A frags mi4-7; stage B(t+3); 16 MFMA; counted vmcnt ----
#pragma unroll
    for (int mi = 0; mi < 4; ++mi)
      aF1[mi] = *(const bf16x8*)&As[(wmr + (mi + 4) * 16 + m16) * 32 + fsw];
    if (t + 3 < NT) STAGE_B(t + 3);
    __builtin_amdgcn_s_barrier();
    __builtin_amdgcn_s_setprio(1);
#pragma unroll
    for (int mi = 0; mi < 4; ++mi)
#pragma unroll
      for (int ni = 0; ni < 4; ++ni)
        acc[mi + 4][ni] = __builtin_amdgcn_mfma_f32_16x16x32_bf16(aF1[mi], bF[ni], acc[mi + 4][ni], 0, 0, 0);
    __builtin_amdgcn_s_setprio(0);

    // step boundary: ensure step t+1's loads landed before its ds_reads.
    // Steady state keeps steps t+2,t+3 (8 loads) in flight -- never drain.
    const int rem = NT - 1 - t;
    if (rem >= 3)      asm volatile("s_waitcnt vmcnt(8)" ::: "memory");
    else if (rem == 2) asm volatile("s_waitcnt vmcnt(4)" ::: "memory");
    else if (rem == 1) asm volatile("s_waitcnt vmcnt(0)" ::: "memory");
    __builtin_amdgcn_s_barrier();
    __builtin_amdgcn_sched_barrier(0);
  }
#undef STAGE_A
#undef STAGE_B

  // ---- fused RoPE epilogue (identical math to the verified 128-tile one) --
  const int sect = colBase >> 10;  // 0=Q,1=K,2=V (tile is 256-wide: uniform)
#pragma unroll
  for (int mi = 0; mi < 8; ++mi)
#pragma unroll
    for (int ni = 0; ni < 4; ++ni) {
      const int col = colBase + wnr + ni * 16 + m16;
      const int rb  = rowBase + wmr + mi * 16 + q4 * 4;
      if (sect == 2) {
        const int hd = col - 2048;
#pragma unroll
        for (int r = 0; r < 4; ++r)
          Vb[(size_t)(rb + r) * 1024 + hd] = f2bf(acc[mi][ni][r]);
      } else {
        const int cc = col & 1023;
        const int h = cc >> 6, d = cc & 63, j = d >> 1;
        const float sgn = (m16 & 1) ? 1.f : -1.f;
        short* dstp = (sect == 0) ? Qb : Kb;
        const float scl = (sect == 0) ? (0.125f * 1.44269504f) : 1.f;
#pragma unroll
        for (int r = 0; r < 4; ++r) {
          const int row = rb + r;
          const int s = row & (S_LEN - 1), bidx = row >> 11;
          float2 cs = tab[s * 32 + j];
          float self = acc[mi][ni][r];
          float part = __shfl_xor(self, 1);
          float o = (self * cs.x + sgn * part * cs.y) * scl;
          dstp[((size_t)((bidx * 16 + h) * S_LEN + s)) * 64 + d] = f2bf(o);
        }
      }
    }
}

// ---------------------------------------------------------------------------
// Generic bf16 GEMM C[M,N] = A[M,K].B[N,K]^T (m97 structure) -- used for the
// output projection only (EPI=0).
// ---------------------------------------------------------------------------
template <int BM, typename OutT, int EPI>
__global__ __launch_bounds__(256) void gemm_ll(const short* __restrict__ A,
                                               const short* __restrict__ B,
                                               OutT* __restrict__ C,
                                               const float2* __restrict__ tab,
                                               short* __restrict__ Qb,
                                               short* __restrict__ Kb,
                                               short* __restrict__ Vb,
                                               int M, int N, int K) {
  constexpr int MI = BM / 32;
  constexpr int AI = BM / 64;
  __shared__ short As[BM * 32];
  __shared__ short Bs[128 * 32];
  const int tid  = threadIdx.x;
  const int lane = tid & 63;
  const int wv   = tid >> 6;
  const int wm   = (wv >> 1) * (BM / 2);
  const int wn   = (wv & 1) * 64;
  const int m16  = lane & 15;
  const int q4   = lane >> 4;
  const int rowBase = blockIdx.y * BM;
  const int colBase = blockIdx.x * 128;
  const int lrow = lane >> 2;
  const int lchk = (lane & 3) ^ ((lane >> 3) & 3);
  const int fsw  = (q4 ^ ((m16 >> 1) & 3)) * 8;

  f32x4 acc[MI][4];
#pragma unroll
  for (int i = 0; i < MI; ++i)
#pragma unroll
    for (int j = 0; j < 4; ++j) acc[i][j] = (f32x4){0.f, 0.f, 0.f, 0.f};

  const short* Agl = A + (size_t)rowBase * K;
  const short* Bgl = B + (size_t)colBase * K;

  for (int kk = 0; kk < K; kk += 32) {
#pragma unroll
    for (int i = 0; i < AI; ++i) {
      const int r0 = (wv * AI + i) * 16;
      GLD_LDS16(Agl + (size_t)(r0 + lrow) * K + kk + lchk * 8, &As[r0 * 32]);
    }
#pragma unroll
    for (int i = 0; i < 2; ++i) {
      const int r0 = (wv * 2 + i) * 16;
      GLD_LDS16(Bgl + (size_t)(r0 + lrow) * K + kk + lchk * 8, &Bs[r0 * 32]);
    }
    __syncthreads();

    bf16x8 af[MI], bfv[4];
#pragma unroll
    for (int mi = 0; mi < MI; ++mi)
      af[mi] = *(const bf16x8*)&As[(wm + mi * 16 + m16) * 32 + fsw];
#pragma unroll
    for (int ni = 0; ni < 4; ++ni)
      bfv[ni] = *(const bf16x8*)&Bs[(wn + ni * 16 + m16) * 32 + fsw];
#pragma unroll
    for (int mi = 0; mi < MI; ++mi)
#pragma unroll
      for (int ni = 0; ni < 4; ++ni)
        acc[mi][ni] = __builtin_amdgcn_mfma_f32_16x16x32_bf16(af[mi], bfv[ni], acc[mi][ni], 0, 0, 0);
    __syncthreads();
  }

  if constexpr (EPI == 0) {
#pragma unroll
    for (int mi = 0; mi < MI; ++mi)
#pragma unroll
      for (int ni = 0; ni < 4; ++ni) {
        const int rbase = rowBase + wm + mi * 16 + q4 * 4;
        const int cidx  = colBase + wn + ni * 16 + m16;
#pragma unroll
        for (int r = 0; r < 4; ++r) {
          float v = acc[mi][ni][r];
          if constexpr (sizeof(OutT) == 2)
            C[(size_t)(rbase + r) * N + cidx] = (OutT)f2bf(v);
          else
            C[(size_t)(rbase + r) * N + cidx] = (OutT)v;
        }
      }
  } else {
    const int sect = colBase >> 10;
#pragma unroll
    for (int mi = 0; mi < MI; ++mi)
#pragma unroll
      for (int ni = 0; ni < 4; ++ni) {
        const int col = colBase + wn + ni * 16 + m16;
        const int rb  = rowBase + wm + mi * 16 + q4 * 4;
        if (sect == 2) {
          const int hd = col - 2048;
#pragma unroll
          for (int r = 0; r < 4; ++r)
            Vb[(size_t)(rb + r) * 1024 + hd] = f2bf(acc[mi][ni][r]);
        } else {
          const int cc = col & 1023;
          const int h = cc >> 6, d = cc & 63, j = d >> 1;
          const float sgn = (m16 & 1) ? 1.f : -1.f;
          short* dstp = (sect == 0) ? Qb : Kb;
          const float scl = (sect == 0) ? (0.125f * 1.44269504f) : 1.f;
#pragma unroll
          for (int r = 0; r < 4; ++r) {
            const int row = rb + r;
            const int s = row & (S_LEN - 1), bidx = row >> 11;
            float2 cs = tab[s * 32 + j];
            float self = acc[mi][ni][r];
            float part = __shfl_xor(self, 1);
            float o = (self * cs.x + sgn * part * cs.y) * scl;
            dstp[((size_t)((bidx * 16 + h) * S_LEN + s)) * 64 + d] = f2bf(o);
          }
        }
      }
  }
}

// ---------------------------------------------------------------------------
// V transpose: Vb bf16 [4096][1024] -> VT bf16 [bh][64][2048], keys sigma64-
// permuted within each 64-block (matches attn's register-P layout).
// ---------------------------------------------------------------------------
__global__ __launch_bounds__(256) void prep_v(const short* __restrict__ Vb,
                                              short* __restrict__ VT) {
  __shared__ __align__(16) short VtL[64 * 72];
  const int tid = threadIdx.x;
  const int st  = blockIdx.x, bh = blockIdx.y;
  const int b   = bh >> 4, h = bh & 15;
  const int r   = tid >> 2, seg = tid & 3;
  const int s   = st * 64 + r;
  const int pr  = sigma64(r);
  {
    const short* vsrc = Vb + (size_t)(b * S_LEN + s) * 1024 + h * 64 + seg * 16;
    short in[16];
    *(bf16x8*)&in[0] = ((const bf16x8*)vsrc)[0];
    *(bf16x8*)&in[8] = ((const bf16x8*)vsrc)[1];
#pragma unroll
    for (int d = 0; d < 16; ++d)
      VtL[(seg * 16 + d) * 72 + pr] = in[d];
  }
  __syncthreads();
  short* vdst = VT + ((size_t)bh * 64 + r) * S_LEN + st * 64 + seg * 16;
  ((bf16x8*)vdst)[0] = *(bf16x8*)&VtL[r * 72 + seg * 16];
  ((bf16x8*)vdst)[1] = *(bf16x8*)&VtL[r * 72 + seg * 16 + 8];
}

// ---------------------------------------------------------------------------
// MFMA flash attention (causal), fixed-shift softmax, register-P (transposed).
// ---------------------------------------------------------------------------
__global__ __launch_bounds__(256, 2) void attn_mfma(const short* __restrict__ Qb,
                                                    const short* __restrict__ Kb,
                                                    const short* __restrict__ VT,
                                                    short* __restrict__ attnb) {
  __shared__ __align__(16) short Smem[9216];
  short* Ks = Smem;
  short* Vs = Smem + 64 * 72;
  const int tid  = threadIdx.x;
  const int lane = tid & 63;
  const int w    = tid >> 6;
  const int m16  = lane & 15;
  const int q4   = lane >> 4;
  const int bh   = blockIdx.x;
  const int jtx  = blockIdx.y;
  const int jt   = (jtx < 8) ? (15 - jtx) : (jtx - 8);
  const int b    = bh >> 4, h = bh & 15;
  const short* Qh = Qb + (size_t)bh * S_LEN * 64;
  const short* Kh = Kb + (size_t)bh * S_LEN * 64;
  const short* Vh = VT + (size_t)bh * 64 * S_LEN;

  const int srow = tid >> 3;
  const int seg  = tid & 7;

  const bf16x8 ones = {16256, 16256, 16256, 16256, 16256, 16256, 16256, 16256};

  const int q0 = jt * 128;
  const int ktiles = 2 * jt + 2;

  bf16x8 qf[2][2];
#pragma unroll
  for (int n = 0; n < 2; ++n)
#pragma unroll
    for (int ks = 0; ks < 2; ++ks)
      qf[n][ks] = *(const bf16x8*)(Qh + (size_t)(q0 + w * 32 + n * 16 + m16) * 64 + ks * 32 + q4 * 8);

  f32x4 O[2][4], Lacc[2];
#pragma unroll
  for (int n = 0; n < 2; ++n) {
    Lacc[n] = (f32x4){0.f, 0.f, 0.f, 0.f};
#pragma unroll
    for (int c = 0; c < 4; ++c) O[n][c] = (f32x4){0.f, 0.f, 0.f, 0.f};
  }

  bf16x8 kst[2], vst[2];
#pragma unroll
  for (int i = 0; i < 2; ++i) {
    kst[i] = *(const bf16x8*)(Kh + (size_t)(i * 32 + srow) * 64 + seg * 8);
    vst[i] = *(const bf16x8*)(Vh + (size_t)(i * 32 + srow) * S_LEN + seg * 8);
  }

  for (int t = 0; t < ktiles; ++t) {
#pragma unroll
    for (int i = 0; i < 2; ++i) {
      *(bf16x8*)&Ks[(i * 32 + srow) * 72 + seg * 8] = kst[i];
      *(bf16x8*)&Vs[(i * 32 + srow) * 72 + seg * 8] = vst[i];
    }
    __syncthreads();

    if (t + 1 < ktiles) {
#pragma unroll
      for (int i = 0; i < 2; ++i) {
        kst[i] = *(const bf16x8*)(Kh + (size_t)((t + 1) * 64 + i * 32 + srow) * 64 + seg * 8);
        vst[i] = *(const bf16x8*)(Vh + (size_t)(i * 32 + srow) * S_LEN + (t + 1) * 64 + seg * 8);
      }
    }

    f32x4 sc[2][4];
#pragma unroll
    for (int n = 0; n < 2; ++n)
#pragma unroll
      for (int c = 0; c < 4; ++c) sc[n][c] = (f32x4){0.f, 0.f, 0.f, 0.f};
#pragma unroll
    for (int ks = 0; ks < 2; ++ks) {
#pragma unroll
      for (int c = 0; c < 4; ++c) {
        bf16x8 kf = *(const bf16x8*)&Ks[(c * 16 + m16) * 72 + ks * 32 + q4 * 8];
#pragma unroll
        for (int n = 0; n < 2; ++n)
          sc[n][c] = __builtin_amdgcn_mfma_f32_16x16x32_bf16(kf, qf[n][ks], sc[n][c], 0, 0, 0);
      }
    }

    if (t >= ktiles - 2) {
#pragma unroll
      for (int n = 0; n < 2; ++n)
#pragma unroll
        for (int c = 0; c < 4; ++c) {
          const int qg = q0 + w * 32 + n * 16 + m16;
#pragma unroll
          for (int rr = 0; rr < 4; ++rr) {
            const int kg = t * 64 + c * 16 + q4 * 4 + rr;
            if (kg > qg) sc[n][c][rr] = -1e30f;
          }
        }
    }

    bf16x8 pb[2][2];
#pragma unroll
    for (int n = 0; n < 2; ++n) {
#pragma unroll
      for (int c = 0; c < 4; ++c) sc[n][c] = exp2s4(sc[n][c]);
      uintx4 u0 = {pkbf(sc[n][0][0], sc[n][0][1]), pkbf(sc[n][0][2], sc[n][0][3]),
                   pkbf(sc[n][1][0], sc[n][1][1]), pkbf(sc[n][1][2], sc[n][1][3])};
      uintx4 u1 = {pkbf(sc[n][2][0], sc[n][2][1]), pkbf(sc[n][2][2], sc[n][2][3]),
                   pkbf(sc[n][3][0], sc[n][3][1]), pkbf(sc[n][3][2], sc[n][3][3])};
      pb[n][0] = __builtin_bit_cast(bf16x8, u0);
      pb[n][1] = __builtin_bit_cast(bf16x8, u1);
    }

#pragma unroll
    for (int ch = 0; ch < 2; ++ch) {
#pragma unroll
      for (int c2 = 0; c2 < 4; ++c2) {
        bf16x8 va = *(const bf16x8*)&Vs[(c2 * 16 + m16) * 72 + ch * 32 + q4 * 8];
#pragma unroll
        for (int n = 0; n < 2; ++n)
          O[n][c2] = __builtin_amdgcn_mfma_f32_16x16x32_bf16(va, pb[n][ch], O[n][c2], 0, 0, 0);
      }
#pragma unroll
      for (int n = 0; n < 2; ++n)
        Lacc[n] = __builtin_amdgcn_mfma_f32_16x16x32_bf16(ones, pb[n][ch], Lacc[n], 0, 0, 0);
    }
    __syncthreads();
  }

#pragma unroll
  for (int n = 0; n < 2; ++n) {
    const float inv = __frcp_rn(Lacc[n][0]);
#pragma unroll
    for (int c2 = 0; c2 < 4; ++c2) {
      uintx2 uo = {pkbf(O[n][c2][0] * inv, O[n][c2][1] * inv),
                   pkbf(O[n][c2][2] * inv, O[n][c2][3] * inv)};
      *(shortx4*)&Smem[(w * 32 + n * 16 + m16) * 72 + c2 * 16 + q4 * 4] =
          __builtin_bit_cast(shortx4, uo);
    }
  }
  __syncthreads();
  {
    const int row = tid >> 1, hf = tid & 1;
    const short* src = &Smem[row * 72 + hf * 32];
    short* dst = attnb + (size_t)(b * S_LEN + q0 + row) * 1024 + h * 64 + hf * 32;
    ((bf16x8*)dst)[0] = ((const bf16x8*)src)[0];
    ((bf16x8*)dst)[1] = ((const bf16x8*)src)[1];
    ((bf16x8*)dst)[2] = ((const bf16x8*)src)[2];
    ((bf16x8*)dst)[3] = ((const bf16x8*)src)[3];
  }
}

// ---------------------------------------------------------------------------
extern "C" void kernel_launch(void* const* d_in, const int* in_sizes, int n_in,
                              void* d_out, int out_size, void* d_ws, size_t ws_size,
                              hipStream_t stream) {
  const float* X    = (const float*)d_in[0];
  const int*   tok  = (const int*)d_in[1];
  const float* Wqkv = (const float*)d_in[2];
  const float* Wo   = (const float*)d_in[3];
  float* out = (float*)d_out;

  char* w = (char*)d_ws;
  float2* table = (float2*)w;                                  // 512 KB
  short*  Qb    = (short*)(w + 524288);                        // 8.39 MB
  short*  Kb    = Qb + 4194304;                                // 8.39 MB
  short*  VTt   = Kb + 4194304;                                // 8.39 MB
  short*  Vb    = VTt + 4194304;                               // 8.39 MB
  short*  Xb    = Vb + 4194304;                                // 8.39 MB
  short*  Wqkvb = Xb + 4194304;                                // 6.29 MB
  short*  Wob   = Wqkvb + 3145728;                             // 2.10 MB
  short*  attnb = Wob + 1048576;                               // 8.39 MB

  hipLaunchKernelGGL(init_kernel, dim3(4352), dim3(256), 0, stream,
                     X, Wqkv, Wo, tok, Xb, Wqkvb, Wob, table);
  hipLaunchKernelGGL(gemm256_qkv, dim3(192), dim3(512), 0, stream,
                     Xb, Wqkvb, table, Qb, Kb, Vb);
  hipLaunchKernelGGL(prep_v, dim3(32, 32), dim3(256), 0, stream, Vb, VTt);
  hipLaunchKernelGGL(attn_mfma, dim3(32, 16), dim3(256), 0, stream,
                     Qb, Kb, VTt, attnb);
  hipLaunchKernelGGL((gemm_ll<64, float, 0>), dim3(8, 64), dim3(256), 0, stream,
                     attnb, Wob, out, (const float2*)nullptr,
                     (short*)nullptr, (short*)nullptr, (short*)nullptr,
                     4096, 1024, 1024);
}

// Round 2
// 184.258 us; speedup vs baseline: 1.0167x; 1.0167x over previous
//
#include <hip/hip_runtime.h>
#include <math.h>

// Problem constants (B=2, S=2048, D=1024, H=16, dh=64)
#define S_LEN 2048

using bf16x8  = __attribute__((ext_vector_type(8))) short;  // 8 bf16 (4 VGPRs)
using shortx4 = __attribute__((ext_vector_type(4))) short;  // ds_write_b64
using f32x4   = __attribute__((ext_vector_type(4))) float;  // MFMA accumulator
using uintx4  = __attribute__((ext_vector_type(4))) unsigned;
using uintx2  = __attribute__((ext_vector_type(2))) unsigned;

static __device__ __forceinline__ short f2bf(float f) {
  unsigned u = __float_as_uint(f);
  u += 0x7fffu + ((u >> 16) & 1u);
  return (short)(u >> 16);
}

#if __has_builtin(__builtin_amdgcn_cvt_pk_bf16_f32)
using bf16x2_t = __attribute__((ext_vector_type(2))) __bf16;
static __device__ __forceinline__ unsigned pkbf(float a, float b) {
  bf16x2_t v = __builtin_amdgcn_cvt_pk_bf16_f32(a, b);
  return __builtin_bit_cast(unsigned, v);
}
#else
static __device__ __forceinline__ unsigned pkbf(float a, float b) {
  return (unsigned)(unsigned short)f2bf(a) | ((unsigned)(unsigned short)f2bf(b) << 16);
}
#endif

// Direct global->LDS DMA, 16B per lane. LDS dest = wave-uniform base + lane*16.
#define GLD_LDS16(gptr, lptr)                                                  \
  __builtin_amdgcn_global_load_lds(                                            \
      (__attribute__((address_space(1))) void*)(gptr),                         \
      (__attribute__((address_space(3))) void*)(lptr), 16, 0, 0)

// exp2 shift: softmax is shift-invariant; scores ~N(0,1) so 2^(s*log2e-20)
// never overflows and l ~ 2e-3 stays comfortably normal in fp32.
#define EXP2_SHIFT 20.0f

static __device__ __forceinline__ f32x4 exp2s4(f32x4 a) {
  return (f32x4){__builtin_amdgcn_exp2f(a[0] - EXP2_SHIFT),
                 __builtin_amdgcn_exp2f(a[1] - EXP2_SHIFT),
                 __builtin_amdgcn_exp2f(a[2] - EXP2_SHIFT),
                 __builtin_amdgcn_exp2f(a[3] - EXP2_SHIFT)};
}

// Key permutation for VT: sigma(k) maps true local key -> stored position so
// that S^T C/D regs pack directly into the PV^T B-operand.
// k bits [c1 c0 q1 q0 r1 r0] -> [c1 q1 q0 c0 r1 r0].  Preserves low 2 bits.
static __device__ __forceinline__ int sigma64(int k) {
  return (k & 0x20) | ((k & 0x0C) << 1) | ((k & 0x10) >> 2) | (k & 3);
}

// ---------------------------------------------------------------------------
// Fused init: blocks [0,4096) convert X/Wqkv/Wo fp32->bf16 (8 elem/thread);
// blocks [4096,4352) build the RoPE cos/sin table (fp64 trig for range
// reduction at ang up to ~2047 rad).  Branch is block-uniform.
// ---------------------------------------------------------------------------
__global__ __launch_bounds__(256) void init_kernel(const float* __restrict__ X,
                                                   const float* __restrict__ W1,
                                                   const float* __restrict__ W2,
                                                   const int* __restrict__ tok,
                                                   short* __restrict__ Xb,
                                                   short* __restrict__ W1b,
                                                   short* __restrict__ W2b,
                                                   float2* __restrict__ table) {
  if (blockIdx.x < 4096) {
    size_t idx = (size_t)(blockIdx.x * 256 + threadIdx.x) * 8;
    const float* src;
    short* dst;
    size_t off;
    if (idx < 4194304) { src = X; dst = Xb; off = idx; }
    else if (idx < 4194304 + 3145728) { src = W1; dst = W1b; off = idx - 4194304; }
    else { src = W2; dst = W2b; off = idx - (4194304 + 3145728); }
    float4 a = *(const float4*)(src + off);
    float4 b = *(const float4*)(src + off + 4);
    bf16x8 o = {f2bf(a.x), f2bf(a.y), f2bf(a.z), f2bf(a.w),
                f2bf(b.x), f2bf(b.y), f2bf(b.z), f2bf(b.w)};
    *(bf16x8*)(dst + off) = o;
  } else {
    int i = (blockIdx.x - 4096) * 256 + threadIdx.x;  // [0, 65536)
    int s = i >> 5, j = i & 31;
    double pos = (double)tok[s];
    double ang = pos * pow(10000.0, -(double)j / 32.0);
    table[i] = make_float2((float)cos(ang), (float)sin(ang));
  }
}

// ---------------------------------------------------------------------------
// C[M,N] = A[M,K] * B[N,K]^T  -- bf16 in.  m97 structure + XOR-swizzled LDS
// slots (2-way bank aliasing, free).  BMx128x32 tiles, 256 thr = 4 waves.
// Bijective XCD swizzle on the linearized block id (requires nwg % 8 == 0):
// each XCD gets nwg/8 consecutive ids -> contiguous A-panel rows stay in its
// private L2.
// EPI=0: plain OutT C-write.
// EPI=1 (QKV GEMM): fused epilogue — col section (colBase>>10, block-uniform)
//   0: RoPE via __shfl_xor pair exchange, *QSCALE, write Qb [bh][2048][64]
//   1: RoPE, write Kb [bh][2048][64]
//   2: DIRECT transposed V write: VT [bh][64][2048] with keys sigma64-permuted
//      within each 64-block (replaces the old Vb + prep_v pass).  acc rows
//      rb..rb+3 are 4 consecutive keys; sigma64 preserves low 2 bits and
//      rb%4==0, so the 4 bf16 pack into one aligned 8B store.
// ---------------------------------------------------------------------------
template <int BM, typename OutT, int EPI>
__global__ __launch_bounds__(256) void gemm_ll(const short* __restrict__ A,
                                               const short* __restrict__ B,
                                               OutT* __restrict__ C,
                                               const float2* __restrict__ tab,
                                               short* __restrict__ Qb,
                                               short* __restrict__ Kb,
                                               short* __restrict__ VT,
                                               int M, int N, int K) {
  constexpr int MI = BM / 32;
  constexpr int AI = BM / 64;
  __shared__ short As[BM * 32];
  __shared__ short Bs[128 * 32];
  const int tid  = threadIdx.x;
  const int lane = tid & 63;
  const int wv   = tid >> 6;
  const int wm   = (wv >> 1) * (BM / 2);
  const int wn   = (wv & 1) * 64;
  const int m16  = lane & 15;
  const int q4   = lane >> 4;

  // XCD-aware bijective swizzle (nwg % 8 == 0 for both launches).
  const int nwg = gridDim.x * gridDim.y;
  int bid = blockIdx.y * gridDim.x + blockIdx.x;
  bid = (bid & 7) * (nwg >> 3) + (bid >> 3);
  const int rowBase = (bid / gridDim.x) * BM;
  const int colBase = (bid % gridDim.x) * 128;

  const int lrow = lane >> 2;                        // staging row in 16-row group
  const int lchk = (lane & 3) ^ ((lane >> 3) & 3);   // swizzled k-chunk to fetch
  const int fsw  = (q4 ^ ((m16 >> 1) & 3)) * 8;      // swizzled frag k-offset (shorts)

  f32x4 acc[MI][4];
#pragma unroll
  for (int i = 0; i < MI; ++i)
#pragma unroll
    for (int j = 0; j < 4; ++j) acc[i][j] = (f32x4){0.f, 0.f, 0.f, 0.f};

  const short* Agl = A + (size_t)rowBase * K;
  const short* Bgl = B + (size_t)colBase * K;

  for (int kk = 0; kk < K; kk += 32) {
#pragma unroll
    for (int i = 0; i < AI; ++i) {
      const int r0 = (wv * AI + i) * 16;
      GLD_LDS16(Agl + (size_t)(r0 + lrow) * K + kk + lchk * 8, &As[r0 * 32]);
    }
#pragma unroll
    for (int i = 0; i < 2; ++i) {
      const int r0 = (wv * 2 + i) * 16;
      GLD_LDS16(Bgl + (size_t)(r0 + lrow) * K + kk + lchk * 8, &Bs[r0 * 32]);
    }
    __syncthreads();

    bf16x8 af[MI], bfv[4];
#pragma unroll
    for (int mi = 0; mi < MI; ++mi)
      af[mi] = *(const bf16x8*)&As[(wm + mi * 16 + m16) * 32 + fsw];
#pragma unroll
    for (int ni = 0; ni < 4; ++ni)
      bfv[ni] = *(const bf16x8*)&Bs[(wn + ni * 16 + m16) * 32 + fsw];
#pragma unroll
    for (int mi = 0; mi < MI; ++mi)
#pragma unroll
      for (int ni = 0; ni < 4; ++ni)
        acc[mi][ni] = __builtin_amdgcn_mfma_f32_16x16x32_bf16(af[mi], bfv[ni], acc[mi][ni], 0, 0, 0);
    __syncthreads();
  }

  if constexpr (EPI == 0) {
#pragma unroll
    for (int mi = 0; mi < MI; ++mi)
#pragma unroll
      for (int ni = 0; ni < 4; ++ni) {
        const int rbase = rowBase + wm + mi * 16 + q4 * 4;
        const int cidx  = colBase + wn + ni * 16 + m16;
#pragma unroll
        for (int r = 0; r < 4; ++r) {
          float v = acc[mi][ni][r];
          if constexpr (sizeof(OutT) == 2)
            C[(size_t)(rbase + r) * N + cidx] = (OutT)f2bf(v);
          else
            C[(size_t)(rbase + r) * N + cidx] = (OutT)v;
        }
      }
  } else {
    const int sect = colBase >> 10;  // 0=Q,1=K,2=V (block-uniform; 128 | 1024)
#pragma unroll
    for (int mi = 0; mi < MI; ++mi)
#pragma unroll
      for (int ni = 0; ni < 4; ++ni) {
        const int col = colBase + wn + ni * 16 + m16;
        const int rb  = rowBase + wm + mi * 16 + q4 * 4;   // rb % 4 == 0
        if (sect == 2) {
          // direct transposed+permuted V write: VT[bh][d][ (s&~63) + sigma64(s&63) ]
          const int hd = col - 2048;
          const int h = hd >> 6, d = hd & 63;
          const int b = rb >> 11, s0 = rb & (S_LEN - 1);
          shortx4 pk4 = {f2bf(acc[mi][ni][0]), f2bf(acc[mi][ni][1]),
                         f2bf(acc[mi][ni][2]), f2bf(acc[mi][ni][3])};
          *(shortx4*)(VT + ((size_t)((b * 16 + h) * 64 + d)) * S_LEN +
                      (s0 & ~63) + sigma64(s0 & 63)) = pk4;
        } else {
          const int cc = col & 1023;
          const int h = cc >> 6, d = cc & 63, j = d >> 1;
          const float sgn = (m16 & 1) ? 1.f : -1.f;
          short* dstp = (sect == 0) ? Qb : Kb;
          const float scl = (sect == 0) ? (0.125f * 1.44269504f) : 1.f;
#pragma unroll
          for (int r = 0; r < 4; ++r) {
            const int row = rb + r;
            const int s = row & (S_LEN - 1), bidx = row >> 11;
            float2 cs = tab[s * 32 + j];
            float self = acc[mi][ni][r];
            float part = __shfl_xor(self, 1);
            float o = (self * cs.x + sgn * part * cs.y) * scl;
            dstp[((size_t)((bidx * 16 + h) * S_LEN + s)) * 64 + d] = f2bf(o);
          }
        }
      }
  }
}

// ---------------------------------------------------------------------------
// MFMA flash attention (causal), fixed-shift softmax, REGISTER-P (transposed):
//   S^T = K.Q^T   (A=K frag, B=Q frag; C/D: col=q, row=key)
//   P^T regs pack directly into B-operand of O^T = V^T.P^T because V's keys
//   are sigma64-permuted in VT.  l = ones.P^T via MFMA (all rows = l[q]).
// Block = 256 thr = 4 waves; wave owns 32 q (2 n-frags); q-tile = 128 rows.
// Grid (bh=32, jtx=16); jt = jtx<8 ? 15-jtx : jtx-8 -> uniform per-CU work;
// blockIdx.x % 8 = bh % 8 -> head-per-XCD L2 locality.  2 barriers/iter;
// K/V^T in LDS stride 72; register double-buffer of next tile's loads.
// ---------------------------------------------------------------------------
__global__ __launch_bounds__(256, 2) void attn_mfma(const short* __restrict__ Qb,
                                                    const short* __restrict__ Kb,
                                                    const short* __restrict__ VT,
                                                    short* __restrict__ attnb) {
  __shared__ __align__(16) short Smem[9216];  // [Ks 64x72 | Vs 64x72]; epilogue: [128][72]
  short* Ks = Smem;
  short* Vs = Smem + 64 * 72;
  const int tid  = threadIdx.x;
  const int lane = tid & 63;
  const int w    = tid >> 6;                 // wave 0..3, q rows w*32..w*32+31
  const int m16  = lane & 15;
  const int q4   = lane >> 4;
  const int bh   = blockIdx.x;               // XCD = bh % 8
  const int jtx  = blockIdx.y;
  const int jt   = (jtx < 8) ? (15 - jtx) : (jtx - 8);  // balanced pairing
  const int b    = bh >> 4, h = bh & 15;
  const short* Qh = Qb + (size_t)bh * S_LEN * 64;
  const short* Kh = Kb + (size_t)bh * S_LEN * 64;
  const short* Vh = VT + (size_t)bh * 64 * S_LEN;

  const int srow = tid >> 3;                 // staging row 0..31
  const int seg  = tid & 7;                  // 8-short segment

  const bf16x8 ones = {16256, 16256, 16256, 16256, 16256, 16256, 16256, 16256}; // bf16 1.0

  const int q0 = jt * 128;
  const int ktiles = 2 * jt + 2;

  // Q fragments (B-operand): rows q0+w*32+n*16+m16, d-chunk ks*32+q4*8
  bf16x8 qf[2][2];
#pragma unroll
  for (int n = 0; n < 2; ++n)
#pragma unroll
    for (int ks = 0; ks < 2; ++ks)
      qf[n][ks] = *(const bf16x8*)(Qh + (size_t)(q0 + w * 32 + n * 16 + m16) * 64 + ks * 32 + q4 * 8);

  f32x4 O[2][4], Lacc[2];   // O[n][d-tile c2]: O^T[d=c2*16+q4*4+r][q=m16]
#pragma unroll
  for (int n = 0; n < 2; ++n) {
    Lacc[n] = (f32x4){0.f, 0.f, 0.f, 0.f};
#pragma unroll
    for (int c = 0; c < 4; ++c) O[n][c] = (f32x4){0.f, 0.f, 0.f, 0.f};
  }

  // preload tile 0 into registers (K: 64x64, V^T: 64x64; 2 issues each)
  bf16x8 kst[2], vst[2];
#pragma unroll
  for (int i = 0; i < 2; ++i) {
    kst[i] = *(const bf16x8*)(Kh + (size_t)(i * 32 + srow) * 64 + seg * 8);
    vst[i] = *(const bf16x8*)(Vh + (size_t)(i * 32 + srow) * S_LEN + seg * 8);
  }

  for (int t = 0; t < ktiles; ++t) {
#pragma unroll
    for (int i = 0; i < 2; ++i) {  // commit staged registers to LDS
      *(bf16x8*)&Ks[(i * 32 + srow) * 72 + seg * 8] = kst[i];
      *(bf16x8*)&Vs[(i * 32 + srow) * 72 + seg * 8] = vst[i];
    }
    __syncthreads();

    if (t + 1 < ktiles) {  // overlap next tile's global loads with compute
#pragma unroll
      for (int i = 0; i < 2; ++i) {
        kst[i] = *(const bf16x8*)(Kh + (size_t)((t + 1) * 64 + i * 32 + srow) * 64 + seg * 8);
        vst[i] = *(const bf16x8*)(Vh + (size_t)(i * 32 + srow) * S_LEN + (t + 1) * 64 + seg * 8);
      }
    }

    // ---- S^T = K.Q^T  (lane: col=q=m16, rows=keys c*16+q4*4+r) ----
    f32x4 sc[2][4];
#pragma unroll
    for (int n = 0; n < 2; ++n)
#pragma unroll
      for (int c = 0; c < 4; ++c) sc[n][c] = (f32x4){0.f, 0.f, 0.f, 0.f};
#pragma unroll
    for (int ks = 0; ks < 2; ++ks) {
#pragma unroll
      for (int c = 0; c < 4; ++c) {
        bf16x8 kf = *(const bf16x8*)&Ks[(c * 16 + m16) * 72 + ks * 32 + q4 * 8];
#pragma unroll
        for (int n = 0; n < 2; ++n)
          sc[n][c] = __builtin_amdgcn_mfma_f32_16x16x32_bf16(kf, qf[n][ks], sc[n][c], 0, 0, 0);
      }
    }

    if (t >= ktiles - 2) {  // diagonal region: mask key > q
#pragma unroll
      for (int n = 0; n < 2; ++n)
#pragma unroll
        for (int c = 0; c < 4; ++c) {
          const int qg = q0 + w * 32 + n * 16 + m16;        // global query
#pragma unroll
          for (int rr = 0; rr < 4; ++rr) {
            const int kg = t * 64 + c * 16 + q4 * 4 + rr;   // global key
            if (kg > qg) sc[n][c][rr] = -1e30f;
          }
        }
    }

    // ---- p = exp2(s - SHIFT); pack into PV^T B-operands (sigma layout) ----
    bf16x8 pb[2][2];
#pragma unroll
    for (int n = 0; n < 2; ++n) {
#pragma unroll
      for (int c = 0; c < 4; ++c) sc[n][c] = exp2s4(sc[n][c]);
      uintx4 u0 = {pkbf(sc[n][0][0], sc[n][0][1]), pkbf(sc[n][0][2], sc[n][0][3]),
                   pkbf(sc[n][1][0], sc[n][1][1]), pkbf(sc[n][1][2], sc[n][1][3])};
      uintx4 u1 = {pkbf(sc[n][2][0], sc[n][2][1]), pkbf(sc[n][2][2], sc[n][2][3]),
                   pkbf(sc[n][3][0], sc[n][3][1]), pkbf(sc[n][3][2], sc[n][3][3])};
      pb[n][0] = __builtin_bit_cast(bf16x8, u0);
      pb[n][1] = __builtin_bit_cast(bf16x8, u1);
    }

    // ---- O^T += V^T.P^T ; l = ones.P^T ----
#pragma unroll
    for (int ch = 0; ch < 2; ++ch) {
#pragma unroll
      for (int c2 = 0; c2 < 4; ++c2) {
        bf16x8 va = *(const bf16x8*)&Vs[(c2 * 16 + m16) * 72 + ch * 32 + q4 * 8];
#pragma unroll
        for (int n = 0; n < 2; ++n)
          O[n][c2] = __builtin_amdgcn_mfma_f32_16x16x32_bf16(va, pb[n][ch], O[n][c2], 0, 0, 0);
      }
#pragma unroll
      for (int n = 0; n < 2; ++n)
        Lacc[n] = __builtin_amdgcn_mfma_f32_16x16x32_bf16(ones, pb[n][ch], Lacc[n], 0, 0, 0);
    }
    __syncthreads();  // Ks/Vs reads done before next commit overwrites
  }

  // epilogue: O^T -> LDS [q][d] (reuse Smem), then coalesced bf16 stores.
#pragma unroll
  for (int n = 0; n < 2; ++n) {
    const float inv = __frcp_rn(Lacc[n][0]);  // all rows of Lacc equal l[q=m16]
#pragma unroll
    for (int c2 = 0; c2 < 4; ++c2) {
      uintx2 uo = {pkbf(O[n][c2][0] * inv, O[n][c2][1] * inv),
                   pkbf(O[n][c2][2] * inv, O[n][c2][3] * inv)};
      *(shortx4*)&Smem[(w * 32 + n * 16 + m16) * 72 + c2 * 16 + q4 * 4] =
          __builtin_bit_cast(shortx4, uo);
    }
  }
  __syncthreads();
  {
    const int row = tid >> 1, hf = tid & 1;   // 128 rows x 64 cols
    const short* src = &Smem[row * 72 + hf * 32];
    short* dst = attnb + (size_t)(b * S_LEN + q0 + row) * 1024 + h * 64 + hf * 32;
    ((bf16x8*)dst)[0] = ((const bf16x8*)src)[0];
    ((bf16x8*)dst)[1] = ((const bf16x8*)src)[1];
    ((bf16x8*)dst)[2] = ((const bf16x8*)src)[2];
    ((bf16x8*)dst)[3] = ((const bf16x8*)src)[3];
  }
}

// ---------------------------------------------------------------------------
extern "C" void kernel_launch(void* const* d_in, const int* in_sizes, int n_in,
                              void* d_out, int out_size, void* d_ws, size_t ws_size,
                              hipStream_t stream) {
  const float* X    = (const float*)d_in[0];
  const int*   tok  = (const int*)d_in[1];
  const float* Wqkv = (const float*)d_in[2];
  const float* Wo   = (const float*)d_in[3];
  float* out = (float*)d_out;

  char* w = (char*)d_ws;
  float2* table = (float2*)w;                                  // 512 KB
  short*  Qb    = (short*)(w + 524288);                        // 8.39 MB
  short*  Kb    = Qb + 4194304;                                // 8.39 MB
  short*  VTt   = Kb + 4194304;                                // 8.39 MB (written directly by QKV epilogue)
  short*  Xb    = VTt + 2 * 4194304;                           // 8.39 MB (old Vb slot unused)
  short*  Wqkvb = Xb + 4194304;                                // 6.29 MB
  short*  Wob   = Wqkvb + 3145728;                             // 2.10 MB
  short*  attnb = Wob + 1048576;                               // 8.39 MB

  hipLaunchKernelGGL(init_kernel, dim3(4352), dim3(256), 0, stream,
                     X, Wqkv, Wo, tok, Xb, Wqkvb, Wob, table);
  hipLaunchKernelGGL((gemm_ll<128, short, 1>), dim3(24, 32), dim3(256), 0, stream,
                     Xb, Wqkvb, (short*)nullptr, table, Qb, Kb, VTt, 4096, 3072, 1024);
  hipLaunchKernelGGL(attn_mfma, dim3(32, 16), dim3(256), 0, stream,
                     Qb, Kb, VTt, attnb);
  hipLaunchKernelGGL((gemm_ll<128, float, 0>), dim3(8, 32), dim3(256), 0, stream,
                     attnb, Wob, out, (const float2*)nullptr,
                     (short*)nullptr, (short*)nullptr, (short*)nullptr,
                     4096, 1024, 1024);
}